// Round 2
// baseline (109.683 us; speedup 1.0000x reference)
//
#include <hip/hip_runtime.h>

#define HH 480
#define WW 640
#define HW (HH * WW)
#define NC 3
#define NVX 128            // W/SKIP
#define NVY 96             // H/SKIP
#define NV (NVX * NVY)     // 12288
#define NBX 80
#define NBY 60
#define NB (NBX * NBY)     // 4800
#define NGRP 24                        // point groups (2 slices of 256 each)
#define BINBLOCKS ((NB + 255) / 256)   // 19

// ---------------- kernel 1: fused gather + per-class stable compaction + vote ----------------
// Grid (BINBLOCKS, NGRP) x 256. Each block gathers TWO 256-point slices (512 points)
// into LDS, stable-partitioned by class per slice:
//   [0, n1_0) class1 of slice0 | [n1_0, n1_0+n2_0) class2 of slice0
//   [256, 256+n1_1) class1 of slice1 | [256+n1_1, ...) class2 of slice1
// The vote loops visit class-1 segments (slice0 then slice1) then class-2 segments,
// preserving ascending original-index order within each class (reference fold order).
// No atomics, no zero-init: block writes partial[grp][bin] = {h1,d1,h2,d2}.
//
// Inlier test: ux,uy pre-scaled by 2 so cos>0.5 <=> dot>0 && dot^2 > nx.
// Borderline pairs (|s| < nx*8e-5) recompute the reference's exact IEEE sequence
// with ux = 0.5f*a.z (exact, power-of-2 scale).
__global__ void vote_fused(const int* __restrict__ label,
                           const float* __restrict__ vert,
                           float4* __restrict__ partial,      // [NGRP][NB]
                           int2* __restrict__ groupCounts,    // [NGRP] totals (n1, n2)
                           unsigned int* __restrict__ ticket) {
    __shared__ float4 shA[512];   // vx, vy, 2*ux, 2*uy
    __shared__ float  shD[512];   // dist
    __shared__ int sw1[2][4], sw2[2][4];

    const int tid = threadIdx.x;
    const int lane = tid & 63, w = tid >> 6;
    const unsigned long long lt = (1ull << lane) - 1ull;
    const int grp = blockIdx.y;

    int vls[2]; float uxs[2], uys[2], dss[2], pxs[2], pys[2]; int r1[2], r2[2];
#pragma unroll
    for (int ss = 0; ss < 2; ++ss) {
        const int i = (grp * 2 + ss) * 256 + tid;    // point index in [0, NV)
        const int iy = i >> 7;                       // NVX = 128
        const int ix = i & (NVX - 1);
        const int pix = (5 * iy) * WW + 5 * ix;
        const int vl = label[pix];
        const float* base = vert + (size_t)(vl * 3) * HW + pix;
        vls[ss] = vl;
        uxs[ss] = base[0];
        uys[ss] = base[HW];
        dss[ss] = base[(size_t)2 * HW];
        pxs[ss] = (float)(5 * ix);
        pys[ss] = (float)(5 * iy);
        const unsigned long long m1 = __ballot(vl == 1);
        const unsigned long long m2 = __ballot(vl == 2);
        if (lane == 0) { sw1[ss][w] = __popcll(m1); sw2[ss][w] = __popcll(m2); }
        r1[ss] = __popcll(m1 & lt);
        r2[ss] = __popcll(m2 & lt);
    }
    __syncthreads();
    int n1t[2], n2t[2];
#pragma unroll
    for (int ss = 0; ss < 2; ++ss) {
        n1t[ss] = sw1[ss][0] + sw1[ss][1] + sw1[ss][2] + sw1[ss][3];
        n2t[ss] = sw2[ss][0] + sw2[ss][1] + sw2[ss][2] + sw2[ss][3];
        int o1 = 0, o2 = 0;
        for (int k = 0; k < w; ++k) { o1 += sw1[ss][k]; o2 += sw2[ss][k]; }
        const int basep = ss * 256;
        if (vls[ss] == 1) {
            const int p = basep + o1 + r1[ss];
            shA[p] = make_float4(pxs[ss], pys[ss], 2.0f * uxs[ss], 2.0f * uys[ss]);
            shD[p] = dss[ss];
        } else if (vls[ss] == 2) {
            const int p = basep + n1t[ss] + o2 + r2[ss];
            shA[p] = make_float4(pxs[ss], pys[ss], 2.0f * uxs[ss], 2.0f * uys[ss]);
            shD[p] = dss[ss];
        }
    }
    if (blockIdx.x == 0 && tid == 0) {
        groupCounts[grp] = make_int2(n1t[0] + n1t[1], n2t[0] + n2t[1]);
        if (grp == 0) *ticket = 0u;   // vote_fused fully precedes reduce (stream order)
    }
    __syncthreads();

    const int b = blockIdx.x * 256 + tid;
    const float bxf = (float)(4 + 8 * (b % NBX));
    const float byf = (float)(4 + 8 * (b / NBX));
    float h1 = 0.f, d1 = 0.f, h2 = 0.f, d2 = 0.f;

    // wave-uniform segment bounds -> SGPR loop control
    const int a1e = __builtin_amdgcn_readfirstlane(n1t[0]);
    const int a2e = __builtin_amdgcn_readfirstlane(n1t[0] + n2t[0]);
    const int b1e = __builtin_amdgcn_readfirstlane(256 + n1t[1]);
    const int b2e = __builtin_amdgcn_readfirstlane(256 + n1t[1] + n2t[1]);

#define PAIR_BODY(HACC, DACC)                                                        \
    {                                                                                \
        float4 a = shA[j];                                                           \
        float ddx = bxf - a.x;                                                       \
        float ddy = byf - a.y;                                                       \
        float nx  = __builtin_fmaf(ddx, ddx, __builtin_fmaf(ddy, ddy, 1e-6f));       \
        float dot = __builtin_fmaf(ddx, a.z, ddy * a.w);                             \
        float s   = __builtin_fmaf(dot, dot, -nx);                                   \
        bool v = (dot > 0.0f) & (s > 0.0f);                                          \
        if (__builtin_expect((dot > 0.0f) && (fabsf(s) < nx * 8e-5f), 0)) {          \
            float nxe  = __fadd_rn(__fadd_rn(__fmul_rn(ddx, ddx),                    \
                                             __fmul_rn(ddy, ddy)), 1e-6f);           \
            float inve = __fdiv_rn(1.0f, __fsqrt_rn(nxe));                           \
            float dote = __fadd_rn(__fmul_rn(ddx, 0.5f * a.z),                       \
                                   __fmul_rn(ddy, 0.5f * a.w));                      \
            v = __fmul_rn(dote, inve) > 0.5f;                                        \
        }                                                                            \
        float m = v ? 1.0f : 0.0f;                                                   \
        HACC += m;                                                                   \
        DACC = __builtin_fmaf(m, shD[j], DACC);                                      \
    }

#pragma unroll 4
    for (int j = 0; j < a1e; ++j) PAIR_BODY(h1, d1)        // class1, slice0
#pragma unroll 4
    for (int j = 256; j < b1e; ++j) PAIR_BODY(h1, d1)      // class1, slice1
#pragma unroll 4
    for (int j = a1e; j < a2e; ++j) PAIR_BODY(h2, d2)      // class2, slice0
#pragma unroll 4
    for (int j = b1e; j < b2e; ++j) PAIR_BODY(h2, d2)      // class2, slice1
#undef PAIR_BODY

    if (b < NB) partial[grp * NB + b] = make_float4(h1, d1, h2, d2);
}

// ---------------- kernel 2: slice reduction + argmax + ROI (fused finalize) ----------------
// 19 blocks fold the 24 group partials in ascending group order (left fold), write
// hough (incl. zero class-0 row) and dsum, emit per-block packed argmax candidates,
// then the LAST block (threadfence + atomic ticket) does the final candidate reduce,
// counts, and ROI math on one wave.
__global__ void reduce_finalize(const float4* __restrict__ partial,
                                const int2* __restrict__ groupCounts,
                                float* __restrict__ hough,   // out + 18, [NC][NB]
                                float* __restrict__ dsum,    // [2][NB]
                                unsigned long long* __restrict__ cand, // [BINBLOCKS][2]
                                unsigned int* __restrict__ ticket,
                                const float* __restrict__ meta,
                                const float* __restrict__ extents,
                                float* __restrict__ rois) {
    __shared__ unsigned long long sk1[256], sk2[256];
    __shared__ int sdone;
    const int tid = threadIdx.x;
    const int b = blockIdx.x * 256 + tid;
    unsigned long long k1 = 0ull, k2 = 0ull;
    if (b < NB) {
        float h1 = 0.f, d1 = 0.f, h2 = 0.f, d2 = 0.f;
#pragma unroll 6
        for (int s = 0; s < NGRP; ++s) {
            float4 p = partial[s * NB + b];
            h1 += p.x; d1 += p.y; h2 += p.z; d2 += p.w;
        }
        hough[b] = 0.0f;
        hough[NB + b] = h1;
        hough[2 * NB + b] = h2;
        dsum[b] = d1;
        dsum[NB + b] = d2;
        const unsigned long long idx = (unsigned long long)(unsigned)(NB - 1 - b);
        k1 = ((unsigned long long)__float_as_uint(h1) << 32) | idx;
        k2 = ((unsigned long long)__float_as_uint(h2) << 32) | idx;
    }
    sk1[tid] = k1; sk2[tid] = k2;
    __syncthreads();
    for (int s = 128; s > 0; s >>= 1) {
        if (tid < s) {
            if (sk1[tid + s] > sk1[tid]) sk1[tid] = sk1[tid + s];
            if (sk2[tid + s] > sk2[tid]) sk2[tid] = sk2[tid + s];
        }
        __syncthreads();
    }
    if (tid == 0) {
        cand[blockIdx.x * 2]     = sk1[0];
        cand[blockIdx.x * 2 + 1] = sk2[0];
        __threadfence();                       // publish cand/hough/dsum device-wide
        unsigned prev = atomicAdd(ticket, 1u); // device-scope
        sdone = (prev == (unsigned)(BINBLOCKS - 1)) ? 1 : 0;
    }
    __syncthreads();
    if (sdone == 0 || tid >= 64) return;

    __threadfence();  // acquire: other blocks' cand/dsum writes
    unsigned long long f1 = (tid < BINBLOCKS) ? cand[tid * 2]     : 0ull;
    unsigned long long f2 = (tid < BINBLOCKS) ? cand[tid * 2 + 1] : 0ull;
    int cn1 = 0, cn2 = 0;
    if (tid < NGRP) { int2 c = groupCounts[tid]; cn1 = c.x; cn2 = c.y; }
    for (int off = 32; off > 0; off >>= 1) {
        unsigned long long o1 = __shfl_xor(f1, off);
        unsigned long long o2 = __shfl_xor(f2, off);
        if (o1 > f1) f1 = o1;
        if (o2 > f2) f2 = o2;
        cn1 += __shfl_xor(cn1, off);
        cn2 += __shfl_xor(cn2, off);
    }
    if (tid < NC) {
        const int c = tid;
        float votes; int peak;
        if (c == 0) { votes = 0.0f; peak = 0; }
        else {
            unsigned long long k = (c == 1) ? f1 : f2;
            votes = __uint_as_float((unsigned)(k >> 32));
            peak = NB - 1 - (int)(k & 0xffffffffull);
        }
        const float cntf = (c == 0) ? (float)(NV - cn1 - cn2)
                                    : ((c == 1) ? (float)cn1 : (float)cn2);
        const float ds = (c == 0) ? 0.0f : dsum[(c - 1) * NB + peak];
        const float depth = __fdiv_rn(ds, fmaxf(votes, 1.0f));
        const float cx = (float)(4 + 8 * (peak % NBX));
        const float cy = (float)(4 + 8 * (peak / NBX));
        const float score = __fdiv_rn(votes, fmaxf(cntf, 1.0f));
        const int valid = (cntf > 5.0f) && (score > 0.3f);
        const float fx = meta[0], fy = meta[4];
        const float e0 = extents[c * 3 + 0];
        const float e1 = extents[c * 3 + 1];
        const float e2 = extents[c * 3 + 2];
        const float diag = __fsqrt_rn(__fadd_rn(
            __fadd_rn(__fmul_rn(e0, e0), __fmul_rn(e1, e1)), __fmul_rn(e2, e2)));
        const float sz = fmaxf(fabsf(depth), 0.001f);
        const float bw = __fdiv_rn(fabsf(__fmul_rn(diag, fx)), sz);
        const float bh = __fdiv_rn(fabsf(__fmul_rn(diag, fy)), sz);
        rois[c * 6 + 0] = (float)c;
        rois[c * 6 + 1] = cx - bw * 0.5f;
        rois[c * 6 + 2] = cy - bh * 0.5f;
        rois[c * 6 + 3] = cx + bw * 0.5f;
        rois[c * 6 + 4] = cy + bh * 0.5f;
        rois[c * 6 + 5] = valid ? score : 0.0f;
    }
}

extern "C" void kernel_launch(void* const* d_in, const int* in_sizes, int n_in,
                              void* d_out, int out_size, void* d_ws, size_t ws_size,
                              hipStream_t stream) {
    const int* label = (const int*)d_in[0];
    const float* vert = (const float*)d_in[1];
    const float* meta = (const float*)d_in[2];
    const float* extents = (const float*)d_in[3];
    float* out = (float*)d_out;

    char* ws = (char*)d_ws;
    float4* partial = (float4*)ws;                                   // 1,843,200 B
    size_t off = (size_t)NGRP * NB * 16;
    float* dsum = (float*)(ws + off);                                //    38,400 B
    off += (size_t)2 * NB * 4;
    unsigned long long* cand = (unsigned long long*)(ws + off);      //       304 B
    off += (size_t)2 * BINBLOCKS * 8;
    int2* groupCounts = (int2*)(ws + off);                           //       192 B
    off += (size_t)NGRP * 8;
    unsigned int* ticket = (unsigned int*)(ws + off);                //         4 B

    float* hough = out + NC * 6;  // 3*NB floats; rois occupy out[0..17]

    vote_fused<<<dim3(BINBLOCKS, NGRP), 256, 0, stream>>>(label, vert, partial,
                                                          groupCounts, ticket);
    reduce_finalize<<<BINBLOCKS, 256, 0, stream>>>(partial, groupCounts, hough, dsum,
                                                   cand, ticket, meta, extents, out);
}

// Round 3
// 93.299 us; speedup vs baseline: 1.1756x; 1.1756x over previous
//
#include <hip/hip_runtime.h>

#define HH 480
#define WW 640
#define HW (HH * WW)
#define NC 3
#define NVX 128            // W/SKIP
#define NVY 96             // H/SKIP
#define NV (NVX * NVY)     // 12288
#define NBX 80
#define NBY 60
#define NB (NBX * NBY)     // 4800
#define NSLICE 48                      // point slices (256 each)
#define NBB 38                         // bin blocks (128 bins per block, 2 lanes/bin)
#define BINBLOCKS ((NB + 255) / 256)   // 19 (reduce kernel)

// ---------------- kernel 1: fused gather + per-class compaction + paired vote ----------------
// Grid (NBB, NSLICE) x 256 = 1824 blocks (~7.1 waves/SIMD: the vote loop is a
// dependent VALU chain fed from LDS, so it needs wave-count to hide latency —
// round-2 counters: VALUBusy 29%, Occupancy 17% at 456 blocks).
// Each block gathers its 256-point slice into LDS, stable-partitioned by class
// (class1 at [0,n1), class2 at [n1,n1+n2), ascending original index within class).
// Bins are covered by LANE PAIRS: bin = blockIdx.x*128 + (tid>>1), half = tid&1;
// each half visits every other point of each class segment, then the pair combines
// via __shfl_xor(.,1) and each lane writes one coalesced float2 of the partial.
//
// Inlier test: ux,uy pre-scaled by 2 so cos>0.5 <=> dot>0 && dot^2 > nx.
// Borderline pairs (|s| < nx*8e-5) recompute the reference's exact IEEE sequence
// with ux = 0.5f*a.z (exact, power-of-2 scale).
__global__ void vote_fused(const int* __restrict__ label,
                           const float* __restrict__ vert,
                           float2* __restrict__ partial2,     // [NSLICE][NB][2]
                           int2* __restrict__ sliceCounts,    // [NSLICE] (n1, n2)
                           unsigned int* __restrict__ ticket) {
    __shared__ float4 shA[256];   // vx, vy, 2*ux, 2*uy
    __shared__ float  shD[256];   // dist
    __shared__ int sw1[4], sw2[4];

    const int tid = threadIdx.x;
    const int lane = tid & 63, w = tid >> 6;
    const unsigned long long lt = (1ull << lane) - 1ull;
    const int slice = blockIdx.y;

    const int i = slice * 256 + tid;       // point index in [0, NV)
    const int iy = i >> 7;                 // NVX = 128
    const int ix = i & (NVX - 1);
    const int pix = (5 * iy) * WW + 5 * ix;
    const int vl = label[pix];
    const float* base = vert + (size_t)(vl * 3) * HW + pix;
    const float ux = base[0];
    const float uy = base[HW];
    const float dist = base[(size_t)2 * HW];

    const unsigned long long m1 = __ballot(vl == 1);
    const unsigned long long m2 = __ballot(vl == 2);
    if (lane == 0) { sw1[w] = __popcll(m1); sw2[w] = __popcll(m2); }
    __syncthreads();
    const int n1 = sw1[0] + sw1[1] + sw1[2] + sw1[3];
    const int n2 = sw2[0] + sw2[1] + sw2[2] + sw2[3];
    int o1 = 0, o2 = 0;
    for (int k = 0; k < w; ++k) { o1 += sw1[k]; o2 += sw2[k]; }
    if (vl == 1) {
        const int p = o1 + __popcll(m1 & lt);
        shA[p] = make_float4((float)(5 * ix), (float)(5 * iy), 2.0f * ux, 2.0f * uy);
        shD[p] = dist;
    } else if (vl == 2) {
        const int p = n1 + o2 + __popcll(m2 & lt);
        shA[p] = make_float4((float)(5 * ix), (float)(5 * iy), 2.0f * ux, 2.0f * uy);
        shD[p] = dist;
    }
    if (blockIdx.x == 0 && tid == 0) {
        sliceCounts[slice] = make_int2(n1, n2);
        if (slice == 0) *ticket = 0u;  // vote_fused fully precedes reduce (stream order)
    }
    __syncthreads();

    const int bin = blockIdx.x * 128 + (tid >> 1);
    const int half = tid & 1;
    const float bxf = (float)(4 + 8 * (bin % NBX));
    const float byf = (float)(4 + 8 * (bin / NBX));
    float h1 = 0.f, d1 = 0.f, h2 = 0.f, d2 = 0.f;

    const int e1 = __builtin_amdgcn_readfirstlane(n1);       // wave-uniform bounds
    const int e2 = __builtin_amdgcn_readfirstlane(n1 + n2);

#define PAIR_BODY(HACC, DACC)                                                        \
    {                                                                                \
        float4 a = shA[j];                                                           \
        float ddx = bxf - a.x;                                                       \
        float ddy = byf - a.y;                                                       \
        float nx  = __builtin_fmaf(ddx, ddx, __builtin_fmaf(ddy, ddy, 1e-6f));       \
        float dot = __builtin_fmaf(ddx, a.z, ddy * a.w);                             \
        float s   = __builtin_fmaf(dot, dot, -nx);                                   \
        bool v = (dot > 0.0f) & (s > 0.0f);                                          \
        if (__builtin_expect((dot > 0.0f) && (fabsf(s) < nx * 8e-5f), 0)) {          \
            float nxe  = __fadd_rn(__fadd_rn(__fmul_rn(ddx, ddx),                    \
                                             __fmul_rn(ddy, ddy)), 1e-6f);           \
            float inve = __fdiv_rn(1.0f, __fsqrt_rn(nxe));                           \
            float dote = __fadd_rn(__fmul_rn(ddx, 0.5f * a.z),                       \
                                   __fmul_rn(ddy, 0.5f * a.w));                      \
            v = __fmul_rn(dote, inve) > 0.5f;                                        \
        }                                                                            \
        float m = v ? 1.0f : 0.0f;                                                   \
        HACC += m;                                                                   \
        DACC = __builtin_fmaf(m, shD[j], DACC);                                      \
    }

#pragma unroll 4
    for (int j = half; j < e1; j += 2) PAIR_BODY(h1, d1)          // class1 (even/odd split)
#pragma unroll 4
    for (int j = e1 + half; j < e2; j += 2) PAIR_BODY(h2, d2)     // class2 (even/odd split)
#undef PAIR_BODY

    // pair combine: both lanes end with the full per-bin sums
    h1 += __shfl_xor(h1, 1);
    d1 += __shfl_xor(d1, 1);
    h2 += __shfl_xor(h2, 1);
    d2 += __shfl_xor(d2, 1);
    if (bin < NB) {
        // even lane writes {h1,d1}, odd writes {h2,d2}: fully coalesced,
        // layout == float4 {h1,d1,h2,d2} per bin for the reduce kernel
        const float2 val = half ? make_float2(h2, d2) : make_float2(h1, d1);
        partial2[(size_t)(slice * NB + bin) * 2 + half] = val;
    }
}

// ---------------- kernel 2: slice reduction + argmax + ROI (fused finalize) ----------------
// 19 blocks fold the 48 slice partials in ascending slice order (left fold), write
// hough (incl. zero class-0 row) and dsum, emit per-block packed argmax candidates,
// then the LAST block (threadfence + atomic ticket) does the final candidate reduce,
// counts, and ROI math on one wave.
__global__ void reduce_finalize(const float4* __restrict__ partial,
                                const int2* __restrict__ sliceCounts,
                                float* __restrict__ hough,   // out + 18, [NC][NB]
                                float* __restrict__ dsum,    // [2][NB]
                                unsigned long long* __restrict__ cand, // [BINBLOCKS][2]
                                unsigned int* __restrict__ ticket,
                                const float* __restrict__ meta,
                                const float* __restrict__ extents,
                                float* __restrict__ rois) {
    __shared__ unsigned long long sk1[256], sk2[256];
    __shared__ int sdone;
    const int tid = threadIdx.x;
    const int b = blockIdx.x * 256 + tid;
    unsigned long long k1 = 0ull, k2 = 0ull;
    if (b < NB) {
        float h1 = 0.f, d1 = 0.f, h2 = 0.f, d2 = 0.f;
#pragma unroll 8
        for (int s = 0; s < NSLICE; ++s) {
            float4 p = partial[s * NB + b];
            h1 += p.x; d1 += p.y; h2 += p.z; d2 += p.w;
        }
        hough[b] = 0.0f;
        hough[NB + b] = h1;
        hough[2 * NB + b] = h2;
        dsum[b] = d1;
        dsum[NB + b] = d2;
        const unsigned long long idx = (unsigned long long)(unsigned)(NB - 1 - b);
        k1 = ((unsigned long long)__float_as_uint(h1) << 32) | idx;
        k2 = ((unsigned long long)__float_as_uint(h2) << 32) | idx;
    }
    sk1[tid] = k1; sk2[tid] = k2;
    __syncthreads();
    for (int s = 128; s > 0; s >>= 1) {
        if (tid < s) {
            if (sk1[tid + s] > sk1[tid]) sk1[tid] = sk1[tid + s];
            if (sk2[tid + s] > sk2[tid]) sk2[tid] = sk2[tid + s];
        }
        __syncthreads();
    }
    if (tid == 0) {
        cand[blockIdx.x * 2]     = sk1[0];
        cand[blockIdx.x * 2 + 1] = sk2[0];
        __threadfence();                       // publish cand/hough/dsum device-wide
        unsigned prev = atomicAdd(ticket, 1u); // device-scope
        sdone = (prev == (unsigned)(BINBLOCKS - 1)) ? 1 : 0;
    }
    __syncthreads();
    if (sdone == 0 || tid >= 64) return;

    __threadfence();  // acquire: other blocks' cand/dsum writes
    unsigned long long f1 = (tid < BINBLOCKS) ? cand[tid * 2]     : 0ull;
    unsigned long long f2 = (tid < BINBLOCKS) ? cand[tid * 2 + 1] : 0ull;
    int cn1 = 0, cn2 = 0;
    if (tid < NSLICE) { int2 c = sliceCounts[tid]; cn1 = c.x; cn2 = c.y; }
    for (int off = 32; off > 0; off >>= 1) {
        unsigned long long o1 = __shfl_xor(f1, off);
        unsigned long long o2 = __shfl_xor(f2, off);
        if (o1 > f1) f1 = o1;
        if (o2 > f2) f2 = o2;
        cn1 += __shfl_xor(cn1, off);
        cn2 += __shfl_xor(cn2, off);
    }
    if (tid < NC) {
        const int c = tid;
        float votes; int peak;
        if (c == 0) { votes = 0.0f; peak = 0; }
        else {
            unsigned long long k = (c == 1) ? f1 : f2;
            votes = __uint_as_float((unsigned)(k >> 32));
            peak = NB - 1 - (int)(k & 0xffffffffull);
        }
        const float cntf = (c == 0) ? (float)(NV - cn1 - cn2)
                                    : ((c == 1) ? (float)cn1 : (float)cn2);
        const float ds = (c == 0) ? 0.0f : dsum[(c - 1) * NB + peak];
        const float depth = __fdiv_rn(ds, fmaxf(votes, 1.0f));
        const float cx = (float)(4 + 8 * (peak % NBX));
        const float cy = (float)(4 + 8 * (peak / NBX));
        const float score = __fdiv_rn(votes, fmaxf(cntf, 1.0f));
        const int valid = (cntf > 5.0f) && (score > 0.3f);
        const float fx = meta[0], fy = meta[4];
        const float e0 = extents[c * 3 + 0];
        const float e1 = extents[c * 3 + 1];
        const float e2 = extents[c * 3 + 2];
        const float diag = __fsqrt_rn(__fadd_rn(
            __fadd_rn(__fmul_rn(e0, e0), __fmul_rn(e1, e1)), __fmul_rn(e2, e2)));
        const float sz = fmaxf(fabsf(depth), 0.001f);
        const float bw = __fdiv_rn(fabsf(__fmul_rn(diag, fx)), sz);
        const float bh = __fdiv_rn(fabsf(__fmul_rn(diag, fy)), sz);
        rois[c * 6 + 0] = (float)c;
        rois[c * 6 + 1] = cx - bw * 0.5f;
        rois[c * 6 + 2] = cy - bh * 0.5f;
        rois[c * 6 + 3] = cx + bw * 0.5f;
        rois[c * 6 + 4] = cy + bh * 0.5f;
        rois[c * 6 + 5] = valid ? score : 0.0f;
    }
}

extern "C" void kernel_launch(void* const* d_in, const int* in_sizes, int n_in,
                              void* d_out, int out_size, void* d_ws, size_t ws_size,
                              hipStream_t stream) {
    const int* label = (const int*)d_in[0];
    const float* vert = (const float*)d_in[1];
    const float* meta = (const float*)d_in[2];
    const float* extents = (const float*)d_in[3];
    float* out = (float*)d_out;

    char* ws = (char*)d_ws;
    float2* partial2 = (float2*)ws;                                  // 3,686,400 B
    size_t off = (size_t)NSLICE * NB * 16;
    float* dsum = (float*)(ws + off);                                //    38,400 B
    off += (size_t)2 * NB * 4;
    unsigned long long* cand = (unsigned long long*)(ws + off);      //       304 B
    off += (size_t)2 * BINBLOCKS * 8;
    int2* sliceCounts = (int2*)(ws + off);                           //       384 B
    off += (size_t)NSLICE * 8;
    unsigned int* ticket = (unsigned int*)(ws + off);                //         4 B

    float* hough = out + NC * 6;  // 3*NB floats; rois occupy out[0..17]

    vote_fused<<<dim3(NBB, NSLICE), 256, 0, stream>>>(label, vert, partial2,
                                                      sliceCounts, ticket);
    reduce_finalize<<<BINBLOCKS, 256, 0, stream>>>((const float4*)partial2, sliceCounts,
                                                   hough, dsum, cand, ticket,
                                                   meta, extents, out);
}

// Round 4
// 92.411 us; speedup vs baseline: 1.1869x; 1.0096x over previous
//
#include <hip/hip_runtime.h>

#define HH 480
#define WW 640
#define HW (HH * WW)
#define NC 3
#define NVX 128            // W/SKIP
#define NVY 96             // H/SKIP
#define NV (NVX * NVY)     // 12288
#define NBX 80
#define NBY 60
#define NB (NBX * NBY)     // 4800
#define NSLICE 48                      // point slices (256 each)
#define NBB 38                         // bin blocks (128 bins per block, 2 lanes/bin)
#define BINBLOCKS ((NB + 255) / 256)   // 19 (reduce kernel)

// ---------------- kernel 1: fused gather + per-class compaction + paired vote ----------------
// Grid (NBB, NSLICE) x 256 = 1824 blocks (~7 waves/SIMD to hide the dependent
// VALU chain's latency — round-2 counters showed 29% VALUBusy at 456 blocks).
// Each block gathers its 256-point slice into LDS, stable-partitioned by class
// (class1 at [0,n1), class2 at [n1,n1+n2), ascending original index within class).
// Bins covered by LANE PAIRS: bin = blockIdx.x*128 + (tid>>1), half = tid&1; each
// half visits every other point per class segment; pair combines via __shfl_xor(.,1).
//
// Inlier decision (sign-fused): ux,uy pre-scaled by 2 so cos>0.5 <=> dot>0 && dot^2>nx,
// and r = fma(dot,|dot|,-nx) has r>0 <=> that conjunction (|dot|,-nx are free VOP3
// input modifiers -> 1 fma + 1 cmp replaces 2 cmps + and). Borderline band
// |r| < nx*8e-5 is only reachable when dot>0 (else |r| >= nx), where r == s exactly,
// so the band test needs no dot>0 term; band hits recompute the reference's exact
// IEEE sequence with ux = 0.5f*a.z (exact, power-of-2 scale).
__global__ void vote_fused(const int* __restrict__ label,
                           const float* __restrict__ vert,
                           float2* __restrict__ partial2,     // [NSLICE][NB][2]
                           int2* __restrict__ sliceCounts,    // [NSLICE] (n1, n2)
                           unsigned int* __restrict__ ticket) {
    __shared__ float4 shA[256];   // vx, vy, 2*ux, 2*uy
    __shared__ float  shD[256];   // dist
    __shared__ int sw1[4], sw2[4];

    const int tid = threadIdx.x;
    const int lane = tid & 63, w = tid >> 6;
    const unsigned long long lt = (1ull << lane) - 1ull;
    const int slice = blockIdx.y;

    const int i = slice * 256 + tid;       // point index in [0, NV)
    const int iy = i >> 7;                 // NVX = 128
    const int ix = i & (NVX - 1);
    const int pix = (5 * iy) * WW + 5 * ix;
    const int vl = label[pix];
    const float* base = vert + (size_t)(vl * 3) * HW + pix;
    const float ux = base[0];
    const float uy = base[HW];
    const float dist = base[(size_t)2 * HW];

    const unsigned long long m1 = __ballot(vl == 1);
    const unsigned long long m2 = __ballot(vl == 2);
    if (lane == 0) { sw1[w] = __popcll(m1); sw2[w] = __popcll(m2); }
    __syncthreads();
    const int n1 = sw1[0] + sw1[1] + sw1[2] + sw1[3];
    const int n2 = sw2[0] + sw2[1] + sw2[2] + sw2[3];
    int o1 = 0, o2 = 0;
    for (int k = 0; k < w; ++k) { o1 += sw1[k]; o2 += sw2[k]; }
    if (vl == 1) {
        const int p = o1 + __popcll(m1 & lt);
        shA[p] = make_float4((float)(5 * ix), (float)(5 * iy), 2.0f * ux, 2.0f * uy);
        shD[p] = dist;
    } else if (vl == 2) {
        const int p = n1 + o2 + __popcll(m2 & lt);
        shA[p] = make_float4((float)(5 * ix), (float)(5 * iy), 2.0f * ux, 2.0f * uy);
        shD[p] = dist;
    }
    if (blockIdx.x == 0 && tid == 0) {
        sliceCounts[slice] = make_int2(n1, n2);
        if (slice == 0) *ticket = 0u;  // vote_fused fully precedes reduce (stream order)
    }
    __syncthreads();

    const int bin = blockIdx.x * 128 + (tid >> 1);
    const int half = tid & 1;
    const float bxf = (float)(4 + 8 * (bin % NBX));
    const float byf = (float)(4 + 8 * (bin / NBX));
    float h1 = 0.f, d1 = 0.f, h2 = 0.f, d2 = 0.f;

    const int e1 = __builtin_amdgcn_readfirstlane(n1);       // wave-uniform bounds
    const int e2 = __builtin_amdgcn_readfirstlane(n1 + n2);

#define PAIR_BODY(HACC, DACC)                                                        \
    {                                                                                \
        float4 a = shA[j];                                                           \
        float ddx = bxf - a.x;                                                       \
        float ddy = byf - a.y;                                                       \
        float nx  = __builtin_fmaf(ddx, ddx, __builtin_fmaf(ddy, ddy, 1e-6f));       \
        float dot = __builtin_fmaf(ddx, a.z, ddy * a.w);                             \
        float r   = __builtin_fmaf(dot, fabsf(dot), -nx);                            \
        bool v = r > 0.0f;                                                           \
        if (__builtin_expect(fabsf(r) < nx * 8e-5f, 0)) {                            \
            float nxe  = __fadd_rn(__fadd_rn(__fmul_rn(ddx, ddx),                    \
                                             __fmul_rn(ddy, ddy)), 1e-6f);           \
            float inve = __fdiv_rn(1.0f, __fsqrt_rn(nxe));                           \
            float dote = __fadd_rn(__fmul_rn(ddx, 0.5f * a.z),                       \
                                   __fmul_rn(ddy, 0.5f * a.w));                      \
            v = __fmul_rn(dote, inve) > 0.5f;                                        \
        }                                                                            \
        float m = v ? 1.0f : 0.0f;                                                   \
        HACC += m;                                                                   \
        DACC = __builtin_fmaf(m, shD[j], DACC);                                      \
    }

#pragma unroll 4
    for (int j = half; j < e1; j += 2) PAIR_BODY(h1, d1)          // class1 (even/odd split)
#pragma unroll 4
    for (int j = e1 + half; j < e2; j += 2) PAIR_BODY(h2, d2)     // class2 (even/odd split)
#undef PAIR_BODY

    // pair combine: both lanes end with the full per-bin sums
    h1 += __shfl_xor(h1, 1);
    d1 += __shfl_xor(d1, 1);
    h2 += __shfl_xor(h2, 1);
    d2 += __shfl_xor(d2, 1);
    if (bin < NB) {
        // even lane writes {h1,d1}, odd writes {h2,d2}: fully coalesced,
        // layout == float4 {h1,d1,h2,d2} per bin for the reduce kernel
        const float2 val = half ? make_float2(h2, d2) : make_float2(h1, d1);
        partial2[(size_t)(slice * NB + bin) * 2 + half] = val;
    }
}

// ---------------- kernel 2: slice reduction + argmax + ROI (fused finalize) ----------------
// 19 blocks fold the 48 slice partials in ascending slice order (left fold), write
// hough (incl. zero class-0 row) and dsum, emit per-block packed argmax candidates,
// then the LAST block (threadfence + atomic ticket) does the final candidate reduce,
// counts, and ROI math on one wave. unroll 16: each block is alone on its CU, so
// per-thread MLP (16 outstanding b128 loads) is the only latency hiding available.
__global__ void reduce_finalize(const float4* __restrict__ partial,
                                const int2* __restrict__ sliceCounts,
                                float* __restrict__ hough,   // out + 18, [NC][NB]
                                float* __restrict__ dsum,    // [2][NB]
                                unsigned long long* __restrict__ cand, // [BINBLOCKS][2]
                                unsigned int* __restrict__ ticket,
                                const float* __restrict__ meta,
                                const float* __restrict__ extents,
                                float* __restrict__ rois) {
    __shared__ unsigned long long sk1[256], sk2[256];
    __shared__ int sdone;
    const int tid = threadIdx.x;
    const int b = blockIdx.x * 256 + tid;
    unsigned long long k1 = 0ull, k2 = 0ull;
    if (b < NB) {
        float h1 = 0.f, d1 = 0.f, h2 = 0.f, d2 = 0.f;
#pragma unroll 16
        for (int s = 0; s < NSLICE; ++s) {
            float4 p = partial[s * NB + b];
            h1 += p.x; d1 += p.y; h2 += p.z; d2 += p.w;
        }
        hough[b] = 0.0f;
        hough[NB + b] = h1;
        hough[2 * NB + b] = h2;
        dsum[b] = d1;
        dsum[NB + b] = d2;
        const unsigned long long idx = (unsigned long long)(unsigned)(NB - 1 - b);
        k1 = ((unsigned long long)__float_as_uint(h1) << 32) | idx;
        k2 = ((unsigned long long)__float_as_uint(h2) << 32) | idx;
    }
    sk1[tid] = k1; sk2[tid] = k2;
    __syncthreads();
    for (int s = 128; s > 0; s >>= 1) {
        if (tid < s) {
            if (sk1[tid + s] > sk1[tid]) sk1[tid] = sk1[tid + s];
            if (sk2[tid + s] > sk2[tid]) sk2[tid] = sk2[tid + s];
        }
        __syncthreads();
    }
    if (tid == 0) {
        cand[blockIdx.x * 2]     = sk1[0];
        cand[blockIdx.x * 2 + 1] = sk2[0];
        __threadfence();                       // publish cand/hough/dsum device-wide
        unsigned prev = atomicAdd(ticket, 1u); // device-scope
        sdone = (prev == (unsigned)(BINBLOCKS - 1)) ? 1 : 0;
    }
    __syncthreads();
    if (sdone == 0 || tid >= 64) return;

    __threadfence();  // acquire: other blocks' cand/dsum writes
    unsigned long long f1 = (tid < BINBLOCKS) ? cand[tid * 2]     : 0ull;
    unsigned long long f2 = (tid < BINBLOCKS) ? cand[tid * 2 + 1] : 0ull;
    int cn1 = 0, cn2 = 0;
    if (tid < NSLICE) { int2 c = sliceCounts[tid]; cn1 = c.x; cn2 = c.y; }
    for (int off = 32; off > 0; off >>= 1) {
        unsigned long long o1 = __shfl_xor(f1, off);
        unsigned long long o2 = __shfl_xor(f2, off);
        if (o1 > f1) f1 = o1;
        if (o2 > f2) f2 = o2;
        cn1 += __shfl_xor(cn1, off);
        cn2 += __shfl_xor(cn2, off);
    }
    if (tid < NC) {
        const int c = tid;
        float votes; int peak;
        if (c == 0) { votes = 0.0f; peak = 0; }
        else {
            unsigned long long k = (c == 1) ? f1 : f2;
            votes = __uint_as_float((unsigned)(k >> 32));
            peak = NB - 1 - (int)(k & 0xffffffffull);
        }
        const float cntf = (c == 0) ? (float)(NV - cn1 - cn2)
                                    : ((c == 1) ? (float)cn1 : (float)cn2);
        const float ds = (c == 0) ? 0.0f : dsum[(c - 1) * NB + peak];
        const float depth = __fdiv_rn(ds, fmaxf(votes, 1.0f));
        const float cx = (float)(4 + 8 * (peak % NBX));
        const float cy = (float)(4 + 8 * (peak / NBX));
        const float score = __fdiv_rn(votes, fmaxf(cntf, 1.0f));
        const int valid = (cntf > 5.0f) && (score > 0.3f);
        const float fx = meta[0], fy = meta[4];
        const float e0 = extents[c * 3 + 0];
        const float e1 = extents[c * 3 + 1];
        const float e2 = extents[c * 3 + 2];
        const float diag = __fsqrt_rn(__fadd_rn(
            __fadd_rn(__fmul_rn(e0, e0), __fmul_rn(e1, e1)), __fmul_rn(e2, e2)));
        const float sz = fmaxf(fabsf(depth), 0.001f);
        const float bw = __fdiv_rn(fabsf(__fmul_rn(diag, fx)), sz);
        const float bh = __fdiv_rn(fabsf(__fmul_rn(diag, fy)), sz);
        rois[c * 6 + 0] = (float)c;
        rois[c * 6 + 1] = cx - bw * 0.5f;
        rois[c * 6 + 2] = cy - bh * 0.5f;
        rois[c * 6 + 3] = cx + bw * 0.5f;
        rois[c * 6 + 4] = cy + bh * 0.5f;
        rois[c * 6 + 5] = valid ? score : 0.0f;
    }
}

extern "C" void kernel_launch(void* const* d_in, const int* in_sizes, int n_in,
                              void* d_out, int out_size, void* d_ws, size_t ws_size,
                              hipStream_t stream) {
    const int* label = (const int*)d_in[0];
    const float* vert = (const float*)d_in[1];
    const float* meta = (const float*)d_in[2];
    const float* extents = (const float*)d_in[3];
    float* out = (float*)d_out;

    char* ws = (char*)d_ws;
    float2* partial2 = (float2*)ws;                                  // 3,686,400 B
    size_t off = (size_t)NSLICE * NB * 16;
    float* dsum = (float*)(ws + off);                                //    38,400 B
    off += (size_t)2 * NB * 4;
    unsigned long long* cand = (unsigned long long*)(ws + off);      //       304 B
    off += (size_t)2 * BINBLOCKS * 8;
    int2* sliceCounts = (int2*)(ws + off);                           //       384 B
    off += (size_t)NSLICE * 8;
    unsigned int* ticket = (unsigned int*)(ws + off);                //         4 B

    float* hough = out + NC * 6;  // 3*NB floats; rois occupy out[0..17]

    vote_fused<<<dim3(NBB, NSLICE), 256, 0, stream>>>(label, vert, partial2,
                                                      sliceCounts, ticket);
    reduce_finalize<<<BINBLOCKS, 256, 0, stream>>>((const float4*)partial2, sliceCounts,
                                                   hough, dsum, cand, ticket,
                                                   meta, extents, out);
}

// Round 5
// 92.117 us; speedup vs baseline: 1.1907x; 1.0032x over previous
//
#include <hip/hip_runtime.h>

#define HH 480
#define WW 640
#define HW (HH * WW)
#define NC 3
#define NVX 128            // W/SKIP
#define NVY 96             // H/SKIP
#define NV (NVX * NVY)     // 12288
#define NBX 80
#define NBY 60
#define NB (NBX * NBY)     // 4800
#define NSLICE 48                      // point slices (256 each)
#define NBB 38                         // vote bin blocks (128 bins per block, 2 lanes/bin)
#define RBLOCKS 75                     // reduce blocks (64 bins per block, 4 threads/bin)

// ---------------- kernel 1: fused gather + per-class compaction + paired vote ----------------
// Grid (NBB, NSLICE) x 256 = 1824 blocks (~7 waves/SIMD to hide the dependent
// VALU chain's latency — round-2 counters showed 29% VALUBusy at 456 blocks).
// Each block gathers its 256-point slice into LDS, stable-partitioned by class
// (class1 at [0,n1), class2 at [n1,n1+n2), ascending original index within class).
// Bins covered by LANE PAIRS: bin = blockIdx.x*128 + (tid>>1), half = tid&1; each
// half visits every other point per class segment; pair combines via __shfl_xor(.,1).
// LDS reads in the vote loop are wave-uniform per half -> broadcast, conflict-free.
//
// Inlier decision (sign-fused, ~13 VALU/pair — at the VALU floor): ux,uy pre-scaled
// by 2 so cos>0.5 <=> dot>0 && dot^2>nx, and r = fma(dot,|dot|,-nx) has r>0 <=> that
// conjunction (|dot|,-nx are free VOP3 input modifiers). Borderline band
// |r| < nx*8e-5 is only reachable when dot>0 (else |r| >= nx), where r == s exactly;
// band hits recompute the reference's exact IEEE sequence with ux = 0.5f*a.z
// (exact, power-of-2 scale).
__global__ void vote_fused(const int* __restrict__ label,
                           const float* __restrict__ vert,
                           float2* __restrict__ partial2,     // [NSLICE][NB][2]
                           int2* __restrict__ sliceCounts,    // [NSLICE] (n1, n2)
                           unsigned int* __restrict__ ticket) {
    __shared__ float4 shA[256];   // vx, vy, 2*ux, 2*uy
    __shared__ float  shD[256];   // dist
    __shared__ int sw1[4], sw2[4];

    const int tid = threadIdx.x;
    const int lane = tid & 63, w = tid >> 6;
    const unsigned long long lt = (1ull << lane) - 1ull;
    const int slice = blockIdx.y;

    const int i = slice * 256 + tid;       // point index in [0, NV)
    const int iy = i >> 7;                 // NVX = 128
    const int ix = i & (NVX - 1);
    const int pix = (5 * iy) * WW + 5 * ix;
    const int vl = label[pix];
    const float* base = vert + (size_t)(vl * 3) * HW + pix;
    const float ux = base[0];
    const float uy = base[HW];
    const float dist = base[(size_t)2 * HW];

    const unsigned long long m1 = __ballot(vl == 1);
    const unsigned long long m2 = __ballot(vl == 2);
    if (lane == 0) { sw1[w] = __popcll(m1); sw2[w] = __popcll(m2); }
    __syncthreads();
    const int n1 = sw1[0] + sw1[1] + sw1[2] + sw1[3];
    const int n2 = sw2[0] + sw2[1] + sw2[2] + sw2[3];
    int o1 = 0, o2 = 0;
    for (int k = 0; k < w; ++k) { o1 += sw1[k]; o2 += sw2[k]; }
    if (vl == 1) {
        const int p = o1 + __popcll(m1 & lt);
        shA[p] = make_float4((float)(5 * ix), (float)(5 * iy), 2.0f * ux, 2.0f * uy);
        shD[p] = dist;
    } else if (vl == 2) {
        const int p = n1 + o2 + __popcll(m2 & lt);
        shA[p] = make_float4((float)(5 * ix), (float)(5 * iy), 2.0f * ux, 2.0f * uy);
        shD[p] = dist;
    }
    if (blockIdx.x == 0 && tid == 0) {
        sliceCounts[slice] = make_int2(n1, n2);
        if (slice == 0) *ticket = 0u;  // vote_fused fully precedes reduce (stream order)
    }
    __syncthreads();

    const int bin = blockIdx.x * 128 + (tid >> 1);
    const int half = tid & 1;
    const float bxf = (float)(4 + 8 * (bin % NBX));
    const float byf = (float)(4 + 8 * (bin / NBX));
    float h1 = 0.f, d1 = 0.f, h2 = 0.f, d2 = 0.f;

    const int e1 = __builtin_amdgcn_readfirstlane(n1);       // wave-uniform bounds
    const int e2 = __builtin_amdgcn_readfirstlane(n1 + n2);

#define PAIR_BODY(HACC, DACC)                                                        \
    {                                                                                \
        float4 a = shA[j];                                                           \
        float ddx = bxf - a.x;                                                       \
        float ddy = byf - a.y;                                                       \
        float nx  = __builtin_fmaf(ddx, ddx, __builtin_fmaf(ddy, ddy, 1e-6f));       \
        float dot = __builtin_fmaf(ddx, a.z, ddy * a.w);                             \
        float r   = __builtin_fmaf(dot, fabsf(dot), -nx);                            \
        bool v = r > 0.0f;                                                           \
        if (__builtin_expect(fabsf(r) < nx * 8e-5f, 0)) {                            \
            float nxe  = __fadd_rn(__fadd_rn(__fmul_rn(ddx, ddx),                    \
                                             __fmul_rn(ddy, ddy)), 1e-6f);           \
            float inve = __fdiv_rn(1.0f, __fsqrt_rn(nxe));                           \
            float dote = __fadd_rn(__fmul_rn(ddx, 0.5f * a.z),                       \
                                   __fmul_rn(ddy, 0.5f * a.w));                      \
            v = __fmul_rn(dote, inve) > 0.5f;                                        \
        }                                                                            \
        float m = v ? 1.0f : 0.0f;                                                   \
        HACC += m;                                                                   \
        DACC = __builtin_fmaf(m, shD[j], DACC);                                      \
    }

#pragma unroll 4
    for (int j = half; j < e1; j += 2) PAIR_BODY(h1, d1)          // class1 (even/odd split)
#pragma unroll 4
    for (int j = e1 + half; j < e2; j += 2) PAIR_BODY(h2, d2)     // class2 (even/odd split)
#undef PAIR_BODY

    // pair combine: both lanes end with the full per-bin sums
    h1 += __shfl_xor(h1, 1);
    d1 += __shfl_xor(d1, 1);
    h2 += __shfl_xor(h2, 1);
    d2 += __shfl_xor(d2, 1);
    if (bin < NB) {
        // even lane writes {h1,d1}, odd writes {h2,d2}: fully coalesced,
        // layout == float4 {h1,d1,h2,d2} per bin for the reduce kernel
        const float2 val = half ? make_float2(h2, d2) : make_float2(h1, d1);
        partial2[(size_t)(slice * NB + bin) * 2 + half] = val;
    }
}

// ---------------- kernel 2: slice reduction + argmax + ROI (fused finalize) ----------------
// RBLOCKS=75 blocks, 64 bins/block, 4 THREADS PER BIN (sub = tid&3 handles slices
// s ≡ sub mod 4, 12 loads each — round-4's 19-block version serialized 48 loads/thread
// at 7% CU utilization). LDS combine of the 4 sub-partials, then per-block argmax
// candidates; LAST block (threadfence + atomic ticket) reduces the 75 candidates via
// LDS tree and does counts + ROI math. Summation grouping differs from the reference's
// strict left fold — established as output-exact across rounds 1/2/3 (three different
// bracketings, absmax = 0.0; hough is integer-valued so any order is exact).
__global__ void reduce_finalize(const float4* __restrict__ partial,
                                const int2* __restrict__ sliceCounts,
                                float* __restrict__ hough,   // out + 18, [NC][NB]
                                float* __restrict__ dsum,    // [2][NB]
                                unsigned long long* __restrict__ cand, // [RBLOCKS][2]
                                unsigned int* __restrict__ ticket,
                                const float* __restrict__ meta,
                                const float* __restrict__ extents,
                                float* __restrict__ rois) {
    __shared__ float4 sp[256];
    __shared__ unsigned long long sk1[128], sk2[128];
    __shared__ int sdone;
    const int tid = threadIdx.x;
    const int bin = blockIdx.x * 64 + (tid >> 2);   // 75*64 == NB exactly
    const int sub = tid & 3;

    float h1 = 0.f, d1 = 0.f, h2 = 0.f, d2 = 0.f;
#pragma unroll 12
    for (int s = sub; s < NSLICE; s += 4) {
        float4 p = partial[s * NB + bin];
        h1 += p.x; d1 += p.y; h2 += p.z; d2 += p.w;
    }
    sp[tid] = make_float4(h1, d1, h2, d2);
    __syncthreads();

    if (tid < 128) { sk1[tid] = 0ull; sk2[tid] = 0ull; }
    if (sub == 0) {
        float4 p1 = sp[tid + 1], p2 = sp[tid + 2], p3 = sp[tid + 3];
        h1 += p1.x + p2.x + p3.x;
        d1 += p1.y + p2.y + p3.y;
        h2 += p1.z + p2.z + p3.z;
        d2 += p1.w + p2.w + p3.w;
        hough[bin] = 0.0f;
        hough[NB + bin] = h1;
        hough[2 * NB + bin] = h2;
        dsum[bin] = d1;
        dsum[NB + bin] = d2;
        const unsigned long long idx = (unsigned long long)(unsigned)(NB - 1 - bin);
        sk1[tid >> 2] = ((unsigned long long)__float_as_uint(h1) << 32) | idx;
        sk2[tid >> 2] = ((unsigned long long)__float_as_uint(h2) << 32) | idx;
    }
    __syncthreads();
    for (int s = 32; s > 0; s >>= 1) {              // argmax over the 64 bin-keys
        if (tid < s) {
            if (sk1[tid + s] > sk1[tid]) sk1[tid] = sk1[tid + s];
            if (sk2[tid + s] > sk2[tid]) sk2[tid] = sk2[tid + s];
        }
        __syncthreads();
    }
    if (tid == 0) {
        cand[blockIdx.x * 2]     = sk1[0];
        cand[blockIdx.x * 2 + 1] = sk2[0];
        __threadfence();                       // publish cand/hough/dsum device-wide
        unsigned prev = atomicAdd(ticket, 1u); // device-scope
        sdone = (prev == (unsigned)(RBLOCKS - 1)) ? 1 : 0;
    }
    __syncthreads();
    if (sdone == 0) return;                    // sdone is block-uniform (shared)

    __threadfence();  // acquire: other blocks' cand/dsum writes
    if (tid < 128) {
        sk1[tid] = (tid < RBLOCKS) ? cand[tid * 2]     : 0ull;
        sk2[tid] = (tid < RBLOCKS) ? cand[tid * 2 + 1] : 0ull;
    }
    __syncthreads();
    for (int s = 64; s > 0; s >>= 1) {              // argmax over 75 candidates
        if (tid < s) {
            if (sk1[tid + s] > sk1[tid]) sk1[tid] = sk1[tid + s];
            if (sk2[tid + s] > sk2[tid]) sk2[tid] = sk2[tid + s];
        }
        __syncthreads();
    }
    if (tid >= 64) return;
    int cn1 = 0, cn2 = 0;                           // slice-count sum, one wave
    if (tid < NSLICE) { int2 c = sliceCounts[tid]; cn1 = c.x; cn2 = c.y; }
    for (int off = 32; off > 0; off >>= 1) {
        cn1 += __shfl_xor(cn1, off);
        cn2 += __shfl_xor(cn2, off);
    }
    if (tid < NC) {
        const int c = tid;
        float votes; int peak;
        if (c == 0) { votes = 0.0f; peak = 0; }
        else {
            unsigned long long k = (c == 1) ? sk1[0] : sk2[0];
            votes = __uint_as_float((unsigned)(k >> 32));
            peak = NB - 1 - (int)(k & 0xffffffffull);
        }
        const float cntf = (c == 0) ? (float)(NV - cn1 - cn2)
                                    : ((c == 1) ? (float)cn1 : (float)cn2);
        const float ds = (c == 0) ? 0.0f : dsum[(c - 1) * NB + peak];
        const float depth = __fdiv_rn(ds, fmaxf(votes, 1.0f));
        const float cx = (float)(4 + 8 * (peak % NBX));
        const float cy = (float)(4 + 8 * (peak / NBX));
        const float score = __fdiv_rn(votes, fmaxf(cntf, 1.0f));
        const int valid = (cntf > 5.0f) && (score > 0.3f);
        const float fx = meta[0], fy = meta[4];
        const float e0 = extents[c * 3 + 0];
        const float e1 = extents[c * 3 + 1];
        const float e2 = extents[c * 3 + 2];
        const float diag = __fsqrt_rn(__fadd_rn(
            __fadd_rn(__fmul_rn(e0, e0), __fmul_rn(e1, e1)), __fmul_rn(e2, e2)));
        const float sz = fmaxf(fabsf(depth), 0.001f);
        const float bw = __fdiv_rn(fabsf(__fmul_rn(diag, fx)), sz);
        const float bh = __fdiv_rn(fabsf(__fmul_rn(diag, fy)), sz);
        rois[c * 6 + 0] = (float)c;
        rois[c * 6 + 1] = cx - bw * 0.5f;
        rois[c * 6 + 2] = cy - bh * 0.5f;
        rois[c * 6 + 3] = cx + bw * 0.5f;
        rois[c * 6 + 4] = cy + bh * 0.5f;
        rois[c * 6 + 5] = valid ? score : 0.0f;
    }
}

extern "C" void kernel_launch(void* const* d_in, const int* in_sizes, int n_in,
                              void* d_out, int out_size, void* d_ws, size_t ws_size,
                              hipStream_t stream) {
    const int* label = (const int*)d_in[0];
    const float* vert = (const float*)d_in[1];
    const float* meta = (const float*)d_in[2];
    const float* extents = (const float*)d_in[3];
    float* out = (float*)d_out;

    char* ws = (char*)d_ws;
    float2* partial2 = (float2*)ws;                                  // 3,686,400 B
    size_t off = (size_t)NSLICE * NB * 16;
    float* dsum = (float*)(ws + off);                                //    38,400 B
    off += (size_t)2 * NB * 4;
    unsigned long long* cand = (unsigned long long*)(ws + off);      //     1,200 B
    off += (size_t)2 * RBLOCKS * 8;
    int2* sliceCounts = (int2*)(ws + off);                           //       384 B
    off += (size_t)NSLICE * 8;
    unsigned int* ticket = (unsigned int*)(ws + off);                //         4 B

    float* hough = out + NC * 6;  // 3*NB floats; rois occupy out[0..17]

    vote_fused<<<dim3(NBB, NSLICE), 256, 0, stream>>>(label, vert, partial2,
                                                      sliceCounts, ticket);
    reduce_finalize<<<RBLOCKS, 256, 0, stream>>>((const float4*)partial2, sliceCounts,
                                                 hough, dsum, cand, ticket,
                                                 meta, extents, out);
}